// Round 1
// baseline (169.546 us; speedup 1.0000x reference)
//
#include <hip/hip_runtime.h>
#include <hip/hip_bf16.h>
#include <math.h>

#define QN 128
#define SN 128
#define HN 32
#define CN (QN * SN)
#define BBLK 256   // batch rows per block

// Block: 256 threads, one q, 256 batch rows.
// Thread: 2 consecutive batch rows (bi, bi+1), 16 of the 32 h outputs.
//   bi = b0 + (tid>>1)*2, h0 = (tid&1)*16.
// Lanes tid and tid^1 share the same row pair and cover h halves 0..15 / 16..31;
// they combine via __shfl_xor at the end.
__global__ __launch_bounds__(256, 4)
void divenc_kernel(const float* __restrict__ x,
                   const float* __restrict__ W1,
                   const float* __restrict__ b1,
                   const float* __restrict__ W2,
                   const float* __restrict__ b2,
                   float* __restrict__ out) {
  const int q   = blockIdx.x;
  const int b0  = blockIdx.y * BBLK;
  const int tid = threadIdx.x;

  __shared__ float w1s[SN * HN];  // 16 KB, W1[q] as [s][h]
  __shared__ float w2s[HN];

  // Stage W1[q] (4096 floats) with coalesced float4 loads: 16 per thread.
  {
    const float4* src = reinterpret_cast<const float4*>(W1 + (size_t)q * SN * HN);
    float4* dst = reinterpret_cast<float4*>(w1s);
    #pragma unroll
    for (int i = 0; i < (SN * HN / 4) / 256; ++i)
      dst[tid + i * 256] = src[tid + i * 256];
    if (tid < HN) w2s[tid] = W2[q * HN + tid];
  }
  __syncthreads();

  const int bi = b0 + (tid >> 1) * 2;
  const int h0 = (tid & 1) * 16;

  float acc0[16], acc1[16];
  #pragma unroll
  for (int j = 0; j < 16; ++j) { acc0[j] = 0.f; acc1[j] = 0.f; }

  const float* xr0 = x + (size_t)bi * CN + q * SN;
  const float* xr1 = xr0 + CN;

  for (int s4 = 0; s4 < SN; s4 += 4) {
    float4 xa = *reinterpret_cast<const float4*>(xr0 + s4);
    float4 xb = *reinterpret_cast<const float4*>(xr1 + s4);
    #pragma unroll
    for (int u = 0; u < 4; ++u) {
      const float xv0 = (&xa.x)[u];
      const float xv1 = (&xb.x)[u];
      const float* wrow = &w1s[(s4 + u) * HN + h0];
      #pragma unroll
      for (int j = 0; j < 16; ++j) {
        const float w = wrow[j];
        acc0[j] = fmaf(xv0, w, acc0[j]);
        acc1[j] = fmaf(xv1, w, acc1[j]);
      }
    }
  }

  // Epilogue: + b1, ELU, dot with W2 over this thread's 16 h.
  float s0 = 0.f, s1 = 0.f;
  #pragma unroll
  for (int j = 0; j < 16; ++j) {
    const float bb  = b1[q * HN + h0 + j];
    const float w2v = w2s[h0 + j];
    float v0 = acc0[j] + bb;
    float v1 = acc1[j] + bb;
    v0 = v0 > 0.f ? v0 : expm1f(v0);
    v1 = v1 > 0.f ? v1 : expm1f(v1);
    s0 = fmaf(v0, w2v, s0);
    s1 = fmaf(v1, w2v, s1);
  }

  // Combine the two h halves (lanes tid, tid^1 share the same rows).
  s0 += __shfl_xor(s0, 1);
  s1 += __shfl_xor(s1, 1);

  if ((tid & 1) == 0) {
    const float bias = b2[q];
    out[(size_t)bi * QN + q]       = s0 + bias;
    out[(size_t)(bi + 1) * QN + q] = s1 + bias;
  }
}

extern "C" void kernel_launch(void* const* d_in, const int* in_sizes, int n_in,
                              void* d_out, int out_size, void* d_ws, size_t ws_size,
                              hipStream_t stream) {
  const float* x  = (const float*)d_in[0];
  const float* W1 = (const float*)d_in[1];
  const float* b1 = (const float*)d_in[2];
  const float* W2 = (const float*)d_in[3];
  const float* b2 = (const float*)d_in[4];
  float* out = (float*)d_out;

  const int B = in_sizes[0] / CN;  // 2048
  dim3 grid(QN, B / BBLK);
  divenc_kernel<<<grid, 256, 0, stream>>>(x, W1, b1, W2, b2, out);
}

// Round 2
// 88.241 us; speedup vs baseline: 1.9214x; 1.9214x over previous
//
#include <hip/hip_runtime.h>
#include <hip/hip_bf16.h>
#include <math.h>

#define QN 128
#define SN 128
#define HN 32
#define CN (QN * SN)
#define TILE_R 64            // rows per LDS tile
#define NTILE 4              // tiles per block
#define BBLK (TILE_R * NTILE)  // 256 batch rows per block

// Block: 256 threads (4 waves), one q, 256 batch rows (4 tiles of 64).
// Within a tile: lane = local row (0..63), wave w owns h-octet h0 = w*8.
// W1/b1/W2 operands are wave-uniform -> scalar (SGPR) loads, FMA broadcasts
// from SGPR for free. x is staged coalesced into XOR-swizzled LDS.
__global__ __launch_bounds__(256, 4)
void divenc_kernel(const float* __restrict__ x,
                   const float* __restrict__ W1,
                   const float* __restrict__ b1,
                   const float* __restrict__ W2,
                   const float* __restrict__ b2,
                   float* __restrict__ out) {
  const int q    = blockIdx.x;
  const int b0   = blockIdx.y * BBLK;
  const int tid  = threadIdx.x;
  const int lane = tid & 63;
  const int wid  = __builtin_amdgcn_readfirstlane(tid >> 6);
  const int h0   = wid * 8;  // uniform per wave

  __shared__ float xtile[TILE_R * SN];   // 32 KB, XOR-swizzled rows
  __shared__ float parts[4][TILE_R];     // per-wave partials

  const float* __restrict__ w1q = W1 + (size_t)q * (SN * HN);

  // wave-uniform epilogue params (scalar loads)
  float b1v[8], w2v[8];
  #pragma unroll
  for (int j = 0; j < 8; ++j) {
    b1v[j] = b1[q * HN + h0 + j];
    w2v[j] = W2[q * HN + h0 + j];
  }
  const float b2q = b2[q];

  const float* xbase = x + (size_t)b0 * CN + (size_t)q * SN;

  // ---- stage tile 0 (coalesced: each instr = 8 contiguous 512B row segments)
  float4 stg[8];
  #pragma unroll
  for (int i = 0; i < 8; ++i) {
    const int f = i * 256 + tid;
    const int r = f >> 5, c = f & 31;
    stg[i] = *reinterpret_cast<const float4*>(xbase + (size_t)r * CN + c * 4);
  }
  #pragma unroll
  for (int i = 0; i < 8; ++i) {
    const int f = i * 256 + tid;
    const int r = f >> 5, c = f & 31;
    *reinterpret_cast<float4*>(&xtile[r * SN + ((c ^ (r & 31)) << 2)]) = stg[i];
  }
  __syncthreads();

  for (int t = 0; t < NTILE; ++t) {
    // issue next tile's global loads early (latency hides under compute)
    if (t + 1 < NTILE) {
      const float* nb = xbase + (size_t)(t + 1) * TILE_R * CN;
      #pragma unroll
      for (int i = 0; i < 8; ++i) {
        const int f = i * 256 + tid;
        const int r = f >> 5, c = f & 31;
        stg[i] = *reinterpret_cast<const float4*>(nb + (size_t)r * CN + c * 4);
      }
    }

    // ---- compute: lane's row from LDS, W1 from SGPRs
    float acc[8];
    #pragma unroll
    for (int j = 0; j < 8; ++j) acc[j] = 0.f;

    #pragma unroll 2
    for (int s4 = 0; s4 < SN; s4 += 4) {
      const float4 xv = *reinterpret_cast<const float4*>(
          &xtile[(lane << 7) + (((s4 >> 2) ^ (lane & 31)) << 2)]);
      #pragma unroll
      for (int u = 0; u < 4; ++u) {
        const float xu = (&xv.x)[u];
        const float* __restrict__ wrow = w1q + (s4 + u) * HN + h0;  // uniform addr
        #pragma unroll
        for (int j = 0; j < 8; ++j)
          acc[j] = fmaf(xu, wrow[j], acc[j]);
      }
    }

    // ---- epilogue: +b1, ELU, dot W2 over this wave's 8 h
    float part = 0.f;
    #pragma unroll
    for (int j = 0; j < 8; ++j) {
      float v = acc[j] + b1v[j];
      v = v > 0.f ? v : expm1f(v);
      part = fmaf(v, w2v[j], part);
    }
    parts[wid][lane] = part;
    __syncthreads();  // also fences xtile reads of tile t

    if (wid == 0) {
      const float o = parts[0][lane] + parts[1][lane] + parts[2][lane] +
                      parts[3][lane] + b2q;
      out[(size_t)(b0 + t * TILE_R + lane) * QN + q] = o;
    }

    // ---- write next tile into LDS
    if (t + 1 < NTILE) {
      #pragma unroll
      for (int i = 0; i < 8; ++i) {
        const int f = i * 256 + tid;
        const int r = f >> 5, c = f & 31;
        *reinterpret_cast<float4*>(&xtile[r * SN + ((c ^ (r & 31)) << 2)]) = stg[i];
      }
    }
    __syncthreads();
  }
}

extern "C" void kernel_launch(void* const* d_in, const int* in_sizes, int n_in,
                              void* d_out, int out_size, void* d_ws, size_t ws_size,
                              hipStream_t stream) {
  const float* x  = (const float*)d_in[0];
  const float* W1 = (const float*)d_in[1];
  const float* b1 = (const float*)d_in[2];
  const float* W2 = (const float*)d_in[3];
  const float* b2 = (const float*)d_in[4];
  float* out = (float*)d_out;

  const int B = in_sizes[0] / CN;  // 2048
  dim3 grid(QN, B / BBLK);
  divenc_kernel<<<grid, 256, 0, stream>>>(x, W1, b1, W2, b2, out);
}